// Round 6
// baseline (485.446 us; speedup 1.0000x reference)
//
#include <hip/hip_runtime.h>
#include <stdint.h>

#define N_CUST 500000
#define N_FUND 50000
#define N_EDGE 4000000
#define D_CUST 101
#define HID 64

#define NB   512                              // reorder blocks (measured-good R0)
#define EPB  ((N_EDGE + NB - 1) / NB)         // 7813 edges per block
#define CB   512                              // customers per bucket
#define NBKT ((N_CUST + CB - 1) / CB)         // 977 buckets
#define CAP  5120                             // per-bucket capacity (mean 4096, +16 sigma)
#define GPAD 32                               // gcur padding: 1 counter per 128B line

typedef float float4u __attribute__((ext_vector_type(4), aligned(4)));
using frag_ab = __attribute__((ext_vector_type(8))) short;   // 8 bf16
using frag_cd = __attribute__((ext_vector_type(4))) float;   // 4 f32

struct __align__(16) Accum { float g0, g1, cnt, pad; };

__device__ __forceinline__ short f2bf(float f) {
    unsigned u = __float_as_uint(f);
    u += 0x7fffu + ((u >> 16) & 1u);          // round-to-nearest-even
    return (short)(u >> 16);
}

// ---------------------------------------------------------------------------
// k_gf: gf[f] = relu(x_f[f]*W_fund + b_fund) @ (W_l @ W_out)
// Block 0 additionally precomputes Bt = W_r@W_out, c2 = b_l@W_out + b_out,
// wcb = W_cust in bf16 MFMA B-fragment layout, and zeroes gcur (padded).
// Optional Az != nullptr: zero the 8MB Accum array (fallback path only).
// ---------------------------------------------------------------------------
__global__ __launch_bounds__(256) void k_gf(
    const float* __restrict__ x_fund,
    const float* __restrict__ W_fund,
    const float* __restrict__ b_fund,
    const float* __restrict__ W_l,
    const float* __restrict__ W_r,
    const float* __restrict__ W_out,
    const float* __restrict__ Wc,
    const float* __restrict__ b_l,
    const float* __restrict__ b_out,
    float2* __restrict__ gf,
    frag_ab* __restrict__ wcb,
    float* __restrict__ Bt,
    float* __restrict__ c2,
    unsigned* __restrict__ gcur,
    float4* __restrict__ Az)
{
    __shared__ float sAf[128];
    __shared__ float sWf[64];
    __shared__ float sBf[64];
    int t = threadIdx.x;

    if (Az != nullptr) {
        float4 z4 = make_float4(0.f, 0.f, 0.f, 0.f);
        for (int i = blockIdx.x * 256 + t; i < N_CUST; i += gridDim.x * 256)
            Az[i] = z4;
    }

    if (t < 128) {
        int h = t >> 1, j = t & 1;
        float s = 0.f;
        for (int k = 0; k < 64; ++k)
            s = fmaf(W_l[h * 64 + k], W_out[k * 2 + j], s);
        sAf[t] = s;
    } else if (t < 192) {
        sWf[t - 128] = W_fund[t - 128];
    } else {
        sBf[t - 192] = b_fund[t - 192];
    }
    __syncthreads();

    int f = blockIdx.x * 256 + t;
    if (f < N_FUND) {
        float xf = x_fund[f];
        float g0 = 0.f, g1 = 0.f;
        #pragma unroll
        for (int h = 0; h < 64; ++h) {
            float hf = fmaxf(fmaf(xf, sWf[h], sBf[h]), 0.f);
            g0 = fmaf(hf, sAf[2 * h + 0], g0);
            g1 = fmaf(hf, sAf[2 * h + 1], g1);
        }
        gf[f] = make_float2(g0, g1);
    }

    if (blockIdx.x == 0) {
        for (int k = t; k < NBKT * GPAD; k += 256) gcur[k] = 0u;
        if (t < 128) {
            int h = t >> 1, j = t & 1;
            float s = 0.f;
            for (int k = 0; k < 64; ++k)
                s = fmaf(W_r[h * 64 + k], W_out[k * 2 + j], s);
            Bt[t] = s;
        } else if (t < 130) {
            int j = t - 128;
            float s = b_out[j];
            for (int k = 0; k < 64; ++k)
                s = fmaf(b_l[k], W_out[k * 2 + j], s);
            c2[j] = s;
        }
        // wcb[(nt*4+kc)*64 + lane] = B-fragment for that (nt,kc,lane)
        for (int sidx = t; sidx < 1024; sidx += 256) {
            int fidx = sidx >> 6, l = sidx & 63;
            int c = l & 15, q = l >> 4;
            int nt = fidx >> 2, kc = fidx & 3;
            frag_ab fr;
            #pragma unroll
            for (int j = 0; j < 8; ++j) {
                int kk = kc * 32 + q * 8 + j;
                int h  = nt * 16 + c;
                fr[j] = (kk < D_CUST) ? f2bf(Wc[kk * HID + h]) : (short)0;
            }
            wcb[sidx] = fr;
        }
    }
}

// ---------------------------------------------------------------------------
// k_reorder: R0 (measured-good) flush structure: LDS bucket-sort of each
// block's 7813 edges, contiguous global chunk reservation per bucket,
// coalesced flush via ldsBkt. gcur padded (GPAD). Unchanged from R5.
// rec = src | (dst_local << 16); bucket = dst >> 9; dl = dst & 511.
// ---------------------------------------------------------------------------
__global__ __launch_bounds__(256) void k_reorder(
    const int* __restrict__ src, const int* __restrict__ dst,
    unsigned* __restrict__ gcur, unsigned* __restrict__ recs)
{
    __shared__ unsigned hist[NBKT];
    __shared__ unsigned localOff[NBKT];
    __shared__ unsigned cur[NBKT];
    __shared__ unsigned baseG[NBKT];
    __shared__ unsigned ldsRec[EPB];
    __shared__ unsigned short ldsBkt[EPB];

    int t = threadIdx.x, b = blockIdx.x;
    int e0 = b * EPB, e1 = min(e0 + EPB, N_EDGE);
    int cntE = e1 - e0;

    for (int k = t; k < NBKT; k += 256) hist[k] = 0;
    __syncthreads();
    for (int e = e0 + t; e < e1; e += 256)
        atomicAdd(&hist[((unsigned)dst[e]) >> 9], 1u);
    __syncthreads();

    // one-wave exclusive scan of hist[0..NBKT)
    if (t < 64) {
        unsigned v[16], pre[16], run = 0;
        #pragma unroll
        for (int j = 0; j < 16; ++j) {
            int idx = t * 16 + j;
            v[j] = (idx < NBKT) ? hist[idx] : 0u;
            pre[j] = run; run += v[j];
        }
        unsigned sc = run;
        #pragma unroll
        for (int d = 1; d < 64; d <<= 1) {
            unsigned n = __shfl_up(sc, d, 64);
            if (t >= d) sc += n;
        }
        unsigned lane_excl = sc - run;
        #pragma unroll
        for (int j = 0; j < 16; ++j) {
            int idx = t * 16 + j;
            if (idx < NBKT) {
                localOff[idx] = lane_excl + pre[j];
                cur[idx]      = lane_excl + pre[j];
            }
        }
    }
    __syncthreads();

    // reserve global chunks (one atomic per non-empty bucket, padded counter)
    for (int k = t; k < NBKT; k += 256) {
        unsigned h = hist[k];
        baseG[k] = h ? ((unsigned)k * CAP + atomicAdd(&gcur[k * GPAD], h)) : 0u;
    }

    // LDS scatter
    for (int e = e0 + t; e < e1; e += 256) {
        unsigned d = (unsigned)dst[e];
        unsigned s = (unsigned)src[e];
        unsigned k = d >> 9;
        unsigned p = atomicAdd(&cur[k], 1u);
        ldsRec[p] = s | ((d & 511u) << 16);
        ldsBkt[p] = (unsigned short)k;
    }
    __syncthreads();

    // coalesced flush (bucket-sorted order -> consecutive i = consecutive g)
    for (int i = t; i < cntE; i += 256) {
        unsigned k = ldsBkt[i];
        unsigned g = baseG[k] + (i - localOff[k]);
        if (g < (k + 1u) * CAP) recs[g] = ldsRec[i];
    }
}

// ---------------------------------------------------------------------------
// k_bucket v4: 256 threads, wave-split + work-stealing + in-register epilogue.
//  wave 3   : aggregates records into LDS (s0,s1,scn), then joins GEMM.
//  all waves: steal 16-row tiles from an LDS counter:
//             acc = x@Wc + bc (MFMA);  p[row] = relu(acc)@Bt in REGISTERS
//             via per-lane partials + 4-level shfl_xor over the 16 c-lanes
//             (acc[nt][i] = C[row=q*4+i][col=nt*16+c] -> no z LDS round-trip).
//  barrier; epilogue: out = pbuf + s/cnt.
// LDS 10.3 KB (was 23.8). __launch_bounds__(256,6) pins VGPR<=85 so the
// btv/bfrag registers can't drop residency below the measured 6 blocks/CU.
// ---------------------------------------------------------------------------
__global__ __launch_bounds__(256, 6) void k_bucket(
    const unsigned* __restrict__ recs, const unsigned* __restrict__ gcur,
    const float2* __restrict__ gf,
    const float* __restrict__ x, const float* __restrict__ bc,
    const frag_ab* __restrict__ wcb, const float* __restrict__ Bt,
    const float* __restrict__ c2,
    float2* __restrict__ out)
{
    __shared__ float s0[CB], s1[CB], scn[CB];   // 6 KB
    __shared__ float pbuf[2 * CB];              // 4 KB
    __shared__ int tileCtr;

    int t = threadIdx.x, k = blockIdx.x;
    int w = t >> 6, lane = t & 63;
    int c = lane & 15, q = lane >> 4;

    if (t == 0) tileCtr = 0;
    for (int cc = t; cc < CB; cc += 256) { s0[cc] = 0.f; s1[cc] = 0.f; scn[cc] = 0.f; }
    __syncthreads();

    // per-wave constants (all waves GEMM eventually)
    frag_ab bfrag[16];
    #pragma unroll
    for (int f = 0; f < 16; ++f) bfrag[f] = wcb[f * 64 + lane];
    float btv[8];                                // Bt[(nt*16+c)][j]
    #pragma unroll
    for (int nt = 0; nt < 4; ++nt) {
        btv[2 * nt]     = Bt[(nt * 16 + c) * 2];
        btv[2 * nt + 1] = Bt[(nt * 16 + c) * 2 + 1];
    }
    float bcv[4];
    #pragma unroll
    for (int nt = 0; nt < 4; ++nt) bcv[nt] = bc[nt * 16 + c];
    float c20 = c2[0], c21 = c2[1];

    int cust0 = k * CB;
    int ncust = min(CB, N_CUST - cust0);
    int n_tiles = ncust >> 4;                   // 32, or 18 for last bucket

    if (w == 3) {
        // ------------ aggregation (then joins the steal loop) ------------
        unsigned n = min(gcur[(unsigned)k * GPAD], (unsigned)CAP);
        const unsigned* rp = recs + (size_t)k * CAP;
        unsigned i = (unsigned)lane * 4u;
        for (; i + 4u <= n; i += 256u) {
            uint4 rr = *(const uint4*)(rp + i);
            float2 ga = gf[rr.x & 0xFFFFu];
            float2 gb = gf[rr.y & 0xFFFFu];
            float2 gc = gf[rr.z & 0xFFFFu];
            float2 gd = gf[rr.w & 0xFFFFu];
            unsigned da = rr.x >> 16, db = rr.y >> 16;
            unsigned dc = rr.z >> 16, dd = rr.w >> 16;
            atomicAdd(&s0[da], ga.x); atomicAdd(&s1[da], ga.y); atomicAdd(&scn[da], 1.f);
            atomicAdd(&s0[db], gb.x); atomicAdd(&s1[db], gb.y); atomicAdd(&scn[db], 1.f);
            atomicAdd(&s0[dc], gc.x); atomicAdd(&s1[dc], gc.y); atomicAdd(&scn[dc], 1.f);
            atomicAdd(&s0[dd], gd.x); atomicAdd(&s1[dd], gd.y); atomicAdd(&scn[dd], 1.f);
        }
        unsigned base = n & ~3u;
        if ((unsigned)lane < (n & 3u)) {
            unsigned r = rp[base + lane];
            float2 g = gf[r & 0xFFFFu];
            unsigned dl = r >> 16;
            atomicAdd(&s0[dl], g.x); atomicAdd(&s1[dl], g.y); atomicAdd(&scn[dl], 1.f);
        }
    }

    // ------------ work-stealing GEMM tiles ------------
    for (;;) {
        int tl;
        if (lane == 0) tl = atomicAdd(&tileCtr, 1);
        tl = __shfl(tl, 0, 64);
        if (tl >= n_tiles) break;

        int row = cust0 + tl * 16 + c;
        const float* xr = x + (size_t)row * D_CUST;
        frag_ab af[4];
        #pragma unroll
        for (int kc = 0; kc < 3; ++kc) {
            float4u lo = *(const float4u*)(xr + kc * 32 + q * 8);
            float4u hi = *(const float4u*)(xr + kc * 32 + q * 8 + 4);
            frag_ab f;
            f[0]=f2bf(lo[0]); f[1]=f2bf(lo[1]); f[2]=f2bf(lo[2]); f[3]=f2bf(lo[3]);
            f[4]=f2bf(hi[0]); f[5]=f2bf(hi[1]); f[6]=f2bf(hi[2]); f[7]=f2bf(hi[3]);
            af[kc] = f;
        }
        {   // tail k = 96..127: only q==0 lanes hold valid k (96..100)
            frag_ab f = {0,0,0,0,0,0,0,0};
            if (q == 0) {
                float4u lo = *(const float4u*)(xr + 96);
                f[0]=f2bf(lo[0]); f[1]=f2bf(lo[1]); f[2]=f2bf(lo[2]); f[3]=f2bf(lo[3]);
                f[4]=f2bf(xr[100]);
            }
            af[3] = f;
        }
        frag_cd acc[4];
        #pragma unroll
        for (int nt = 0; nt < 4; ++nt)
            acc[nt] = (frag_cd){bcv[nt], bcv[nt], bcv[nt], bcv[nt]};
        #pragma unroll
        for (int kc = 0; kc < 4; ++kc)
            #pragma unroll
            for (int nt = 0; nt < 4; ++nt)
                acc[nt] = __builtin_amdgcn_mfma_f32_16x16x32_bf16(
                    af[kc], bfrag[nt * 4 + kc], acc[nt], 0, 0, 0);

        // in-register epilogue: p_j[row=q*4+i] = sum_c sum_nt relu(acc)*Bt
        #pragma unroll
        for (int i = 0; i < 4; ++i) {
            float p0 = 0.f, p1 = 0.f;
            #pragma unroll
            for (int nt = 0; nt < 4; ++nt) {
                float zv = fmaxf(acc[nt][i], 0.f);
                p0 = fmaf(zv, btv[2 * nt],     p0);
                p1 = fmaf(zv, btv[2 * nt + 1], p1);
            }
            #pragma unroll
            for (int m = 1; m < 16; m <<= 1) {
                p0 += __shfl_xor(p0, m, 16);
                p1 += __shfl_xor(p1, m, 16);
            }
            if (c == 0) {
                int lrow = tl * 16 + q * 4 + i;
                pbuf[2 * lrow]     = p0 + c20;
                pbuf[2 * lrow + 1] = p1 + c21;
            }
        }
    }
    __syncthreads();

    // epilogue: combine GEMM result with neighbor mean, coalesced write
    for (int cc = t; cc < ncust; cc += 256) {
        float inv = 1.0f / fmaxf(scn[cc], 1.0f);
        out[cust0 + cc] = make_float2(fmaf(s0[cc], inv, pbuf[2 * cc]),
                                      fmaf(s1[cc], inv, pbuf[2 * cc + 1]));
    }
}

// ---------------------------------------------------------------------------
// Fallback-path kernels (direct global atomics) if ws too small for recs.
// ---------------------------------------------------------------------------
__global__ __launch_bounds__(256) void k_scatter_direct(
    const int* __restrict__ src, const int* __restrict__ dst,
    const float2* __restrict__ gf, Accum* __restrict__ A)
{
    int stride = gridDim.x * 256;
    for (int e = blockIdx.x * 256 + threadIdx.x; e < N_EDGE; e += stride) {
        int s = src[e], d = dst[e];
        float2 g = gf[s];
        unsafeAtomicAdd(&A[d].g0, g.x);
        unsafeAtomicAdd(&A[d].g1, g.y);
        unsafeAtomicAdd(&A[d].cnt, 1.0f);
    }
}

__global__ __launch_bounds__(256) void k_mean(
    const Accum* __restrict__ A, float2* __restrict__ mean2)
{
    int i = blockIdx.x * 256 + threadIdx.x;
    if (i < N_CUST) {
        Accum a = A[i];
        float inv = 1.0f / fmaxf(a.cnt, 1.0f);
        mean2[i] = make_float2(a.g0 * inv, a.g1 * inv);
    }
}

__global__ __launch_bounds__(256) void k_gemm(
    const float* __restrict__ x, const float* __restrict__ bc,
    const frag_ab* __restrict__ wcb, const float* __restrict__ Bt,
    const float* __restrict__ c2, const float2* __restrict__ mean2,
    float2* __restrict__ out)
{
    __shared__ float sBt[128];
    __shared__ float zb[4][16 * 68];

    int t = threadIdx.x;
    int w = t >> 6, lane = t & 63;
    int c = lane & 15, q = lane >> 4;
    float* z = zb[w];

    if (t < 128) sBt[t] = Bt[t];
    frag_ab bfrag[16];
    #pragma unroll
    for (int f = 0; f < 16; ++f) bfrag[f] = wcb[f * 64 + lane];
    float bcv[4];
    #pragma unroll
    for (int nt = 0; nt < 4; ++nt) bcv[nt] = bc[nt * 16 + c];
    float c20 = c2[0], c21 = c2[1];
    __syncthreads();

    const int NT = N_CUST / 16;
    for (int tl = blockIdx.x * 4 + w; tl < NT; tl += gridDim.x * 4) {
        int row0 = tl * 16;
        const float* xr = x + (size_t)(row0 + c) * D_CUST;
        frag_ab af[4];
        #pragma unroll
        for (int kc = 0; kc < 3; ++kc) {
            float4u lo = *(const float4u*)(xr + kc * 32 + q * 8);
            float4u hi = *(const float4u*)(xr + kc * 32 + q * 8 + 4);
            frag_ab f;
            f[0]=f2bf(lo[0]); f[1]=f2bf(lo[1]); f[2]=f2bf(lo[2]); f[3]=f2bf(lo[3]);
            f[4]=f2bf(hi[0]); f[5]=f2bf(hi[1]); f[6]=f2bf(hi[2]); f[7]=f2bf(hi[3]);
            af[kc] = f;
        }
        {
            frag_ab f = {0,0,0,0,0,0,0,0};
            if (q == 0) {
                float4u lo = *(const float4u*)(xr + 96);
                f[0]=f2bf(lo[0]); f[1]=f2bf(lo[1]); f[2]=f2bf(lo[2]); f[3]=f2bf(lo[3]);
                f[4]=f2bf(xr[100]);
            }
            af[3] = f;
        }
        frag_cd acc[4];
        #pragma unroll
        for (int nt = 0; nt < 4; ++nt)
            acc[nt] = (frag_cd){bcv[nt], bcv[nt], bcv[nt], bcv[nt]};
        #pragma unroll
        for (int kc = 0; kc < 4; ++kc)
            #pragma unroll
            for (int nt = 0; nt < 4; ++nt)
                acc[nt] = __builtin_amdgcn_mfma_f32_16x16x32_bf16(
                    af[kc], bfrag[nt * 4 + kc], acc[nt], 0, 0, 0);
        #pragma unroll
        for (int nt = 0; nt < 4; ++nt)
            #pragma unroll
            for (int i = 0; i < 4; ++i)
                z[(q * 4 + i) * 68 + nt * 16 + c] = fmaxf(acc[nt][i], 0.f);
        float p0 = 0.f, p1 = 0.f;
        #pragma unroll
        for (int j4 = 0; j4 < 4; ++j4) {
            float4u zv = *(const float4u*)(z + c * 68 + q * 16 + j4 * 4);
            float4u b0 = *(const float4u*)(sBt + q * 32 + j4 * 8);
            float4u b1 = *(const float4u*)(sBt + q * 32 + j4 * 8 + 4);
            p0 = fmaf(zv[0], b0[0], p0); p1 = fmaf(zv[0], b0[1], p1);
            p0 = fmaf(zv[1], b0[2], p0); p1 = fmaf(zv[1], b0[3], p1);
            p0 = fmaf(zv[2], b1[0], p0); p1 = fmaf(zv[2], b1[1], p1);
            p0 = fmaf(zv[3], b1[2], p0); p1 = fmaf(zv[3], b1[3], p1);
        }
        p0 += __shfl_xor(p0, 16, 64); p0 += __shfl_xor(p0, 32, 64);
        p1 += __shfl_xor(p1, 16, 64); p1 += __shfl_xor(p1, 32, 64);
        if (q == 0) {
            float2 m = mean2[row0 + c];
            out[row0 + c] = make_float2(p0 + c20 + m.x, p1 + c21 + m.y);
        }
    }
}

// ---------------------------------------------------------------------------
extern "C" void kernel_launch(void* const* d_in, const int* in_sizes, int n_in,
                              void* d_out, int out_size, void* d_ws, size_t ws_size,
                              hipStream_t stream) {
    const float* x_customer = (const float*)d_in[0];
    const float* x_fund     = (const float*)d_in[1];
    const int*   src_fund   = (const int*)d_in[2];
    const int*   dst_cust   = (const int*)d_in[3];
    const float* W_cust     = (const float*)d_in[4];
    const float* b_cust     = (const float*)d_in[5];
    const float* W_fund     = (const float*)d_in[6];
    const float* b_fund     = (const float*)d_in[7];
    const float* W_l        = (const float*)d_in[8];
    const float* b_l        = (const float*)d_in[9];
    const float* W_r        = (const float*)d_in[10];
    const float* W_out      = (const float*)d_in[11];
    const float* b_out      = (const float*)d_in[12];

    char* ws = (char*)d_ws;
    // fast path layout:
    //   recs @ 0          : 977*5120*4 = 20,008,960
    //   gf   @ 20,008,960 :   400,000
    //   wcb  @ 20,408,960 :    16,384
    //   Bt   @ 20,425,344 :       512
    //   c2   @ 20,425,856 :        64
    //   gcur @ 20,425,920 :   125,056  (977*32*4, padded) -> total 20,550,976
    const size_t NEED_FAST = 20550976ull;

    if (ws_size >= NEED_FAST) {
        unsigned* recs = (unsigned*)(ws);
        float2*   gf   = (float2*)  (ws + 20008960);
        frag_ab*  wcb  = (frag_ab*) (ws + 20408960);
        float*    Bt   = (float*)   (ws + 20425344);
        float*    c2   = (float*)   (ws + 20425856);
        unsigned* gcur = (unsigned*)(ws + 20425920);

        k_gf<<<256, 256, 0, stream>>>(
            x_fund, W_fund, b_fund, W_l, W_r, W_out, W_cust, b_l, b_out,
            gf, wcb, Bt, c2, gcur, nullptr);
        k_reorder<<<NB, 256, 0, stream>>>(src_fund, dst_cust, gcur, recs);
        k_bucket<<<NBKT, 256, 0, stream>>>(
            recs, gcur, gf, x_customer, b_cust, wcb, Bt, c2, (float2*)d_out);
    } else {
        // fallback: A 8,000,000 | mean2 4,000,000 | gf 400,000 | wcb 16,384
        //           | Bt 512 | c2 64 | gcur 125,056 -> 12,542,016
        Accum*    A    = (Accum*)   (ws);
        float2*   mn2  = (float2*)  (ws + 8000000);
        float2*   gf   = (float2*)  (ws + 12000000);
        frag_ab*  wcb  = (frag_ab*) (ws + 12400000);
        float*    Bt   = (float*)   (ws + 12416384);
        float*    c2   = (float*)   (ws + 12416896);
        unsigned* gcur = (unsigned*)(ws + 12416960);

        k_gf<<<256, 256, 0, stream>>>(
            x_fund, W_fund, b_fund, W_l, W_r, W_out, W_cust, b_l, b_out,
            gf, wcb, Bt, c2, gcur, (float4*)A);
        k_scatter_direct<<<2048, 256, 0, stream>>>(src_fund, dst_cust, gf, A);
        k_mean<<<(N_CUST + 255) / 256, 256, 0, stream>>>(A, mn2);
        k_gemm<<<2048, 256, 0, stream>>>(
            x_customer, b_cust, wcb, Bt, c2, mn2, (float2*)d_out);
    }
}

// Round 7
// 443.022 us; speedup vs baseline: 1.0958x; 1.0958x over previous
//
#include <hip/hip_runtime.h>
#include <stdint.h>

#define N_CUST 500000
#define N_FUND 50000
#define N_EDGE 4000000
#define D_CUST 101
#define HID 64

#define NB   512                              // reorder blocks (measured-good R0)
#define EPB  ((N_EDGE + NB - 1) / NB)         // 7813 edges per block
#define CB   512                              // customers per bucket
#define NBKT ((N_CUST + CB - 1) / CB)         // 977 buckets
#define CAP  5120                             // per-bucket capacity (mean 4096, +16 sigma)
#define GPAD 32                               // gcur padding: 1 counter per 128B line

typedef float float4u __attribute__((ext_vector_type(4), aligned(4)));
using frag_ab = __attribute__((ext_vector_type(8))) short;   // 8 bf16
using frag_cd = __attribute__((ext_vector_type(4))) float;   // 4 f32

struct __align__(16) Accum { float g0, g1, cnt, pad; };

__device__ __forceinline__ short f2bf(float f) {
    unsigned u = __float_as_uint(f);
    u += 0x7fffu + ((u >> 16) & 1u);          // round-to-nearest-even
    return (short)(u >> 16);
}

// ---------------------------------------------------------------------------
// k_gf: gf[f] = relu(x_f[f]*W_fund + b_fund) @ (W_l @ W_out)
// Block 0 additionally precomputes Bt = W_r@W_out, c2 = b_l@W_out + b_out,
// wcb = W_cust in bf16 MFMA B-fragment layout, and zeroes gcur (padded).
// Optional Az != nullptr: zero the 8MB Accum array (fallback path only).
// ---------------------------------------------------------------------------
__global__ __launch_bounds__(256) void k_gf(
    const float* __restrict__ x_fund,
    const float* __restrict__ W_fund,
    const float* __restrict__ b_fund,
    const float* __restrict__ W_l,
    const float* __restrict__ W_r,
    const float* __restrict__ W_out,
    const float* __restrict__ Wc,
    const float* __restrict__ b_l,
    const float* __restrict__ b_out,
    float2* __restrict__ gf,
    frag_ab* __restrict__ wcb,
    float* __restrict__ Bt,
    float* __restrict__ c2,
    unsigned* __restrict__ gcur,
    float4* __restrict__ Az)
{
    __shared__ float sAf[128];
    __shared__ float sWf[64];
    __shared__ float sBf[64];
    int t = threadIdx.x;

    if (Az != nullptr) {
        float4 z4 = make_float4(0.f, 0.f, 0.f, 0.f);
        for (int i = blockIdx.x * 256 + t; i < N_CUST; i += gridDim.x * 256)
            Az[i] = z4;
    }

    if (t < 128) {
        int h = t >> 1, j = t & 1;
        float s = 0.f;
        for (int k = 0; k < 64; ++k)
            s = fmaf(W_l[h * 64 + k], W_out[k * 2 + j], s);
        sAf[t] = s;
    } else if (t < 192) {
        sWf[t - 128] = W_fund[t - 128];
    } else {
        sBf[t - 192] = b_fund[t - 192];
    }
    __syncthreads();

    int f = blockIdx.x * 256 + t;
    if (f < N_FUND) {
        float xf = x_fund[f];
        float g0 = 0.f, g1 = 0.f;
        #pragma unroll
        for (int h = 0; h < 64; ++h) {
            float hf = fmaxf(fmaf(xf, sWf[h], sBf[h]), 0.f);
            g0 = fmaf(hf, sAf[2 * h + 0], g0);
            g1 = fmaf(hf, sAf[2 * h + 1], g1);
        }
        gf[f] = make_float2(g0, g1);
    }

    if (blockIdx.x == 0) {
        for (int k = t; k < NBKT * GPAD; k += 256) gcur[k] = 0u;
        if (t < 128) {
            int h = t >> 1, j = t & 1;
            float s = 0.f;
            for (int k = 0; k < 64; ++k)
                s = fmaf(W_r[h * 64 + k], W_out[k * 2 + j], s);
            Bt[t] = s;
        } else if (t < 130) {
            int j = t - 128;
            float s = b_out[j];
            for (int k = 0; k < 64; ++k)
                s = fmaf(b_l[k], W_out[k * 2 + j], s);
            c2[j] = s;
        }
        // wcb[(nt*4+kc)*64 + lane] = B-fragment for that (nt,kc,lane)
        for (int sidx = t; sidx < 1024; sidx += 256) {
            int fidx = sidx >> 6, l = sidx & 63;
            int c = l & 15, q = l >> 4;
            int nt = fidx >> 2, kc = fidx & 3;
            frag_ab fr;
            #pragma unroll
            for (int j = 0; j < 8; ++j) {
                int kk = kc * 32 + q * 8 + j;
                int h  = nt * 16 + c;
                fr[j] = (kk < D_CUST) ? f2bf(Wc[kk * HID + h]) : (short)0;
            }
            wcb[sidx] = fr;
        }
    }
}

// ---------------------------------------------------------------------------
// k_reorder: R0 (measured-good) flush structure: LDS bucket-sort of each
// block's 7813 edges, contiguous global chunk reservation per bucket,
// coalesced flush via ldsBkt. gcur padded (GPAD). Unchanged from R5.
// rec = src | (dst_local << 16); bucket = dst >> 9; dl = dst & 511.
// ---------------------------------------------------------------------------
__global__ __launch_bounds__(256) void k_reorder(
    const int* __restrict__ src, const int* __restrict__ dst,
    unsigned* __restrict__ gcur, unsigned* __restrict__ recs)
{
    __shared__ unsigned hist[NBKT];
    __shared__ unsigned localOff[NBKT];
    __shared__ unsigned cur[NBKT];
    __shared__ unsigned baseG[NBKT];
    __shared__ unsigned ldsRec[EPB];
    __shared__ unsigned short ldsBkt[EPB];

    int t = threadIdx.x, b = blockIdx.x;
    int e0 = b * EPB, e1 = min(e0 + EPB, N_EDGE);
    int cntE = e1 - e0;

    for (int k = t; k < NBKT; k += 256) hist[k] = 0;
    __syncthreads();
    for (int e = e0 + t; e < e1; e += 256)
        atomicAdd(&hist[((unsigned)dst[e]) >> 9], 1u);
    __syncthreads();

    // one-wave exclusive scan of hist[0..NBKT)
    if (t < 64) {
        unsigned v[16], pre[16], run = 0;
        #pragma unroll
        for (int j = 0; j < 16; ++j) {
            int idx = t * 16 + j;
            v[j] = (idx < NBKT) ? hist[idx] : 0u;
            pre[j] = run; run += v[j];
        }
        unsigned sc = run;
        #pragma unroll
        for (int d = 1; d < 64; d <<= 1) {
            unsigned n = __shfl_up(sc, d, 64);
            if (t >= d) sc += n;
        }
        unsigned lane_excl = sc - run;
        #pragma unroll
        for (int j = 0; j < 16; ++j) {
            int idx = t * 16 + j;
            if (idx < NBKT) {
                localOff[idx] = lane_excl + pre[j];
                cur[idx]      = lane_excl + pre[j];
            }
        }
    }
    __syncthreads();

    // reserve global chunks (one atomic per non-empty bucket, padded counter)
    for (int k = t; k < NBKT; k += 256) {
        unsigned h = hist[k];
        baseG[k] = h ? ((unsigned)k * CAP + atomicAdd(&gcur[k * GPAD], h)) : 0u;
    }

    // LDS scatter
    for (int e = e0 + t; e < e1; e += 256) {
        unsigned d = (unsigned)dst[e];
        unsigned s = (unsigned)src[e];
        unsigned k = d >> 9;
        unsigned p = atomicAdd(&cur[k], 1u);
        ldsRec[p] = s | ((d & 511u) << 16);
        ldsBkt[p] = (unsigned short)k;
    }
    __syncthreads();

    // coalesced flush (bucket-sorted order -> consecutive i = consecutive g)
    for (int i = t; i < cntE; i += 256) {
        unsigned k = ldsBkt[i];
        unsigned g = baseG[k] + (i - localOff[k]);
        if (g < (k + 1u) * CAP) recs[g] = ldsRec[i];
    }
}

// ---------------------------------------------------------------------------
// k_bucket v5: 256 threads, wave-split + work-stealing + in-register epilogue.
// Identical to R6's v4 EXCEPT: no min-waves occupancy pin. R6's
// __launch_bounds__(256,6) forced the allocator to 40 VGPR -> bfrag spilled
// to scratch (FETCH +225MB, WRITE +58MB, 1.6x slower). R5's identical register
// load compiled to 84 VGPR unpinned with zero spill.
//  wave 3   : aggregates records into LDS (s0,s1,scn), then joins GEMM.
//  all waves: steal 16-row tiles from an LDS counter:
//             acc = x@Wc + bc (MFMA);  p[row] = relu(acc)@Bt in REGISTERS
//             (4-level shfl_xor over the 16 c-lanes; no z LDS round-trip,
//              SQ_LDS_BANK_CONFLICT measured 0).
//  barrier; epilogue: out = pbuf + s/cnt.
// ---------------------------------------------------------------------------
__global__ __launch_bounds__(256) void k_bucket(
    const unsigned* __restrict__ recs, const unsigned* __restrict__ gcur,
    const float2* __restrict__ gf,
    const float* __restrict__ x, const float* __restrict__ bc,
    const frag_ab* __restrict__ wcb, const float* __restrict__ Bt,
    const float* __restrict__ c2,
    float2* __restrict__ out)
{
    __shared__ float s0[CB], s1[CB], scn[CB];   // 6 KB
    __shared__ float pbuf[2 * CB];              // 4 KB
    __shared__ int tileCtr;

    int t = threadIdx.x, k = blockIdx.x;
    int w = t >> 6, lane = t & 63;
    int c = lane & 15, q = lane >> 4;

    if (t == 0) tileCtr = 0;
    for (int cc = t; cc < CB; cc += 256) { s0[cc] = 0.f; s1[cc] = 0.f; scn[cc] = 0.f; }
    __syncthreads();

    // per-wave constants (all waves GEMM eventually)
    frag_ab bfrag[16];
    #pragma unroll
    for (int f = 0; f < 16; ++f) bfrag[f] = wcb[f * 64 + lane];
    float btv[8];                                // Bt[(nt*16+c)][j]
    #pragma unroll
    for (int nt = 0; nt < 4; ++nt) {
        btv[2 * nt]     = Bt[(nt * 16 + c) * 2];
        btv[2 * nt + 1] = Bt[(nt * 16 + c) * 2 + 1];
    }
    float bcv[4];
    #pragma unroll
    for (int nt = 0; nt < 4; ++nt) bcv[nt] = bc[nt * 16 + c];
    float c20 = c2[0], c21 = c2[1];

    int cust0 = k * CB;
    int ncust = min(CB, N_CUST - cust0);
    int n_tiles = ncust >> 4;                   // 32, or 18 for last bucket

    if (w == 3) {
        // ------------ aggregation (then joins the steal loop) ------------
        unsigned n = min(gcur[(unsigned)k * GPAD], (unsigned)CAP);
        const unsigned* rp = recs + (size_t)k * CAP;
        unsigned i = (unsigned)lane * 4u;
        for (; i + 4u <= n; i += 256u) {
            uint4 rr = *(const uint4*)(rp + i);
            float2 ga = gf[rr.x & 0xFFFFu];
            float2 gb = gf[rr.y & 0xFFFFu];
            float2 gc = gf[rr.z & 0xFFFFu];
            float2 gd = gf[rr.w & 0xFFFFu];
            unsigned da = rr.x >> 16, db = rr.y >> 16;
            unsigned dc = rr.z >> 16, dd = rr.w >> 16;
            atomicAdd(&s0[da], ga.x); atomicAdd(&s1[da], ga.y); atomicAdd(&scn[da], 1.f);
            atomicAdd(&s0[db], gb.x); atomicAdd(&s1[db], gb.y); atomicAdd(&scn[db], 1.f);
            atomicAdd(&s0[dc], gc.x); atomicAdd(&s1[dc], gc.y); atomicAdd(&scn[dc], 1.f);
            atomicAdd(&s0[dd], gd.x); atomicAdd(&s1[dd], gd.y); atomicAdd(&scn[dd], 1.f);
        }
        unsigned base = n & ~3u;
        if ((unsigned)lane < (n & 3u)) {
            unsigned r = rp[base + lane];
            float2 g = gf[r & 0xFFFFu];
            unsigned dl = r >> 16;
            atomicAdd(&s0[dl], g.x); atomicAdd(&s1[dl], g.y); atomicAdd(&scn[dl], 1.f);
        }
    }

    // ------------ work-stealing GEMM tiles ------------
    for (;;) {
        int tl;
        if (lane == 0) tl = atomicAdd(&tileCtr, 1);
        tl = __shfl(tl, 0, 64);
        if (tl >= n_tiles) break;

        int row = cust0 + tl * 16 + c;
        const float* xr = x + (size_t)row * D_CUST;
        frag_ab af[4];
        #pragma unroll
        for (int kc = 0; kc < 3; ++kc) {
            float4u lo = *(const float4u*)(xr + kc * 32 + q * 8);
            float4u hi = *(const float4u*)(xr + kc * 32 + q * 8 + 4);
            frag_ab f;
            f[0]=f2bf(lo[0]); f[1]=f2bf(lo[1]); f[2]=f2bf(lo[2]); f[3]=f2bf(lo[3]);
            f[4]=f2bf(hi[0]); f[5]=f2bf(hi[1]); f[6]=f2bf(hi[2]); f[7]=f2bf(hi[3]);
            af[kc] = f;
        }
        {   // tail k = 96..127: only q==0 lanes hold valid k (96..100)
            frag_ab f = {0,0,0,0,0,0,0,0};
            if (q == 0) {
                float4u lo = *(const float4u*)(xr + 96);
                f[0]=f2bf(lo[0]); f[1]=f2bf(lo[1]); f[2]=f2bf(lo[2]); f[3]=f2bf(lo[3]);
                f[4]=f2bf(xr[100]);
            }
            af[3] = f;
        }
        frag_cd acc[4];
        #pragma unroll
        for (int nt = 0; nt < 4; ++nt)
            acc[nt] = (frag_cd){bcv[nt], bcv[nt], bcv[nt], bcv[nt]};
        #pragma unroll
        for (int kc = 0; kc < 4; ++kc)
            #pragma unroll
            for (int nt = 0; nt < 4; ++nt)
                acc[nt] = __builtin_amdgcn_mfma_f32_16x16x32_bf16(
                    af[kc], bfrag[nt * 4 + kc], acc[nt], 0, 0, 0);

        // in-register epilogue: p_j[row=q*4+i] = sum_c sum_nt relu(acc)*Bt
        #pragma unroll
        for (int i = 0; i < 4; ++i) {
            float p0 = 0.f, p1 = 0.f;
            #pragma unroll
            for (int nt = 0; nt < 4; ++nt) {
                float zv = fmaxf(acc[nt][i], 0.f);
                p0 = fmaf(zv, btv[2 * nt],     p0);
                p1 = fmaf(zv, btv[2 * nt + 1], p1);
            }
            #pragma unroll
            for (int m = 1; m < 16; m <<= 1) {
                p0 += __shfl_xor(p0, m, 16);
                p1 += __shfl_xor(p1, m, 16);
            }
            if (c == 0) {
                int lrow = tl * 16 + q * 4 + i;
                pbuf[2 * lrow]     = p0 + c20;
                pbuf[2 * lrow + 1] = p1 + c21;
            }
        }
    }
    __syncthreads();

    // epilogue: combine GEMM result with neighbor mean, coalesced write
    for (int cc = t; cc < ncust; cc += 256) {
        float inv = 1.0f / fmaxf(scn[cc], 1.0f);
        out[cust0 + cc] = make_float2(fmaf(s0[cc], inv, pbuf[2 * cc]),
                                      fmaf(s1[cc], inv, pbuf[2 * cc + 1]));
    }
}

// ---------------------------------------------------------------------------
// Fallback-path kernels (direct global atomics) if ws too small for recs.
// ---------------------------------------------------------------------------
__global__ __launch_bounds__(256) void k_scatter_direct(
    const int* __restrict__ src, const int* __restrict__ dst,
    const float2* __restrict__ gf, Accum* __restrict__ A)
{
    int stride = gridDim.x * 256;
    for (int e = blockIdx.x * 256 + threadIdx.x; e < N_EDGE; e += stride) {
        int s = src[e], d = dst[e];
        float2 g = gf[s];
        unsafeAtomicAdd(&A[d].g0, g.x);
        unsafeAtomicAdd(&A[d].g1, g.y);
        unsafeAtomicAdd(&A[d].cnt, 1.0f);
    }
}

__global__ __launch_bounds__(256) void k_mean(
    const Accum* __restrict__ A, float2* __restrict__ mean2)
{
    int i = blockIdx.x * 256 + threadIdx.x;
    if (i < N_CUST) {
        Accum a = A[i];
        float inv = 1.0f / fmaxf(a.cnt, 1.0f);
        mean2[i] = make_float2(a.g0 * inv, a.g1 * inv);
    }
}

__global__ __launch_bounds__(256) void k_gemm(
    const float* __restrict__ x, const float* __restrict__ bc,
    const frag_ab* __restrict__ wcb, const float* __restrict__ Bt,
    const float* __restrict__ c2, const float2* __restrict__ mean2,
    float2* __restrict__ out)
{
    __shared__ float sBt[128];
    __shared__ float zb[4][16 * 68];

    int t = threadIdx.x;
    int w = t >> 6, lane = t & 63;
    int c = lane & 15, q = lane >> 4;
    float* z = zb[w];

    if (t < 128) sBt[t] = Bt[t];
    frag_ab bfrag[16];
    #pragma unroll
    for (int f = 0; f < 16; ++f) bfrag[f] = wcb[f * 64 + lane];
    float bcv[4];
    #pragma unroll
    for (int nt = 0; nt < 4; ++nt) bcv[nt] = bc[nt * 16 + c];
    float c20 = c2[0], c21 = c2[1];
    __syncthreads();

    const int NT = N_CUST / 16;
    for (int tl = blockIdx.x * 4 + w; tl < NT; tl += gridDim.x * 4) {
        int row0 = tl * 16;
        const float* xr = x + (size_t)(row0 + c) * D_CUST;
        frag_ab af[4];
        #pragma unroll
        for (int kc = 0; kc < 3; ++kc) {
            float4u lo = *(const float4u*)(xr + kc * 32 + q * 8);
            float4u hi = *(const float4u*)(xr + kc * 32 + q * 8 + 4);
            frag_ab f;
            f[0]=f2bf(lo[0]); f[1]=f2bf(lo[1]); f[2]=f2bf(lo[2]); f[3]=f2bf(lo[3]);
            f[4]=f2bf(hi[0]); f[5]=f2bf(hi[1]); f[6]=f2bf(hi[2]); f[7]=f2bf(hi[3]);
            af[kc] = f;
        }
        {
            frag_ab f = {0,0,0,0,0,0,0,0};
            if (q == 0) {
                float4u lo = *(const float4u*)(xr + 96);
                f[0]=f2bf(lo[0]); f[1]=f2bf(lo[1]); f[2]=f2bf(lo[2]); f[3]=f2bf(lo[3]);
                f[4]=f2bf(xr[100]);
            }
            af[3] = f;
        }
        frag_cd acc[4];
        #pragma unroll
        for (int nt = 0; nt < 4; ++nt)
            acc[nt] = (frag_cd){bcv[nt], bcv[nt], bcv[nt], bcv[nt]};
        #pragma unroll
        for (int kc = 0; kc < 4; ++kc)
            #pragma unroll
            for (int nt = 0; nt < 4; ++nt)
                acc[nt] = __builtin_amdgcn_mfma_f32_16x16x32_bf16(
                    af[kc], bfrag[nt * 4 + kc], acc[nt], 0, 0, 0);
        #pragma unroll
        for (int nt = 0; nt < 4; ++nt)
            #pragma unroll
            for (int i = 0; i < 4; ++i)
                z[(q * 4 + i) * 68 + nt * 16 + c] = fmaxf(acc[nt][i], 0.f);
        float p0 = 0.f, p1 = 0.f;
        #pragma unroll
        for (int j4 = 0; j4 < 4; ++j4) {
            float4u zv = *(const float4u*)(z + c * 68 + q * 16 + j4 * 4);
            float4u b0 = *(const float4u*)(sBt + q * 32 + j4 * 8);
            float4u b1 = *(const float4u*)(sBt + q * 32 + j4 * 8 + 4);
            p0 = fmaf(zv[0], b0[0], p0); p1 = fmaf(zv[0], b0[1], p1);
            p0 = fmaf(zv[1], b0[2], p0); p1 = fmaf(zv[1], b0[3], p1);
            p0 = fmaf(zv[2], b1[0], p0); p1 = fmaf(zv[2], b1[1], p1);
            p0 = fmaf(zv[3], b1[2], p0); p1 = fmaf(zv[3], b1[3], p1);
        }
        p0 += __shfl_xor(p0, 16, 64); p0 += __shfl_xor(p0, 32, 64);
        p1 += __shfl_xor(p1, 16, 64); p1 += __shfl_xor(p1, 32, 64);
        if (q == 0) {
            float2 m = mean2[row0 + c];
            out[row0 + c] = make_float2(p0 + c20 + m.x, p1 + c21 + m.y);
        }
    }
}

// ---------------------------------------------------------------------------
extern "C" void kernel_launch(void* const* d_in, const int* in_sizes, int n_in,
                              void* d_out, int out_size, void* d_ws, size_t ws_size,
                              hipStream_t stream) {
    const float* x_customer = (const float*)d_in[0];
    const float* x_fund     = (const float*)d_in[1];
    const int*   src_fund   = (const int*)d_in[2];
    const int*   dst_cust   = (const int*)d_in[3];
    const float* W_cust     = (const float*)d_in[4];
    const float* b_cust     = (const float*)d_in[5];
    const float* W_fund     = (const float*)d_in[6];
    const float* b_fund     = (const float*)d_in[7];
    const float* W_l        = (const float*)d_in[8];
    const float* b_l        = (const float*)d_in[9];
    const float* W_r        = (const float*)d_in[10];
    const float* W_out      = (const float*)d_in[11];
    const float* b_out      = (const float*)d_in[12];

    char* ws = (char*)d_ws;
    // fast path layout:
    //   recs @ 0          : 977*5120*4 = 20,008,960
    //   gf   @ 20,008,960 :   400,000
    //   wcb  @ 20,408,960 :    16,384
    //   Bt   @ 20,425,344 :       512
    //   c2   @ 20,425,856 :        64
    //   gcur @ 20,425,920 :   125,056  (977*32*4, padded) -> total 20,550,976
    const size_t NEED_FAST = 20550976ull;

    if (ws_size >= NEED_FAST) {
        unsigned* recs = (unsigned*)(ws);
        float2*   gf   = (float2*)  (ws + 20008960);
        frag_ab*  wcb  = (frag_ab*) (ws + 20408960);
        float*    Bt   = (float*)   (ws + 20425344);
        float*    c2   = (float*)   (ws + 20425856);
        unsigned* gcur = (unsigned*)(ws + 20425920);

        k_gf<<<256, 256, 0, stream>>>(
            x_fund, W_fund, b_fund, W_l, W_r, W_out, W_cust, b_l, b_out,
            gf, wcb, Bt, c2, gcur, nullptr);
        k_reorder<<<NB, 256, 0, stream>>>(src_fund, dst_cust, gcur, recs);
        k_bucket<<<NBKT, 256, 0, stream>>>(
            recs, gcur, gf, x_customer, b_cust, wcb, Bt, c2, (float2*)d_out);
    } else {
        // fallback: A 8,000,000 | mean2 4,000,000 | gf 400,000 | wcb 16,384
        //           | Bt 512 | c2 64 | gcur 125,056 -> 12,542,016
        Accum*    A    = (Accum*)   (ws);
        float2*   mn2  = (float2*)  (ws + 8000000);
        float2*   gf   = (float2*)  (ws + 12000000);
        frag_ab*  wcb  = (frag_ab*) (ws + 12400000);
        float*    Bt   = (float*)   (ws + 12416384);
        float*    c2   = (float*)   (ws + 12416896);
        unsigned* gcur = (unsigned*)(ws + 12416960);

        k_gf<<<256, 256, 0, stream>>>(
            x_fund, W_fund, b_fund, W_l, W_r, W_out, W_cust, b_l, b_out,
            gf, wcb, Bt, c2, gcur, (float4*)A);
        k_scatter_direct<<<2048, 256, 0, stream>>>(src_fund, dst_cust, gf, A);
        k_mean<<<(N_CUST + 255) / 256, 256, 0, stream>>>(A, mn2);
        k_gemm<<<2048, 256, 0, stream>>>(
            x_customer, b_cust, wcb, Bt, c2, mn2, (float2*)d_out);
    }
}

// Round 8
// 428.459 us; speedup vs baseline: 1.1330x; 1.0340x over previous
//
#include <hip/hip_runtime.h>
#include <stdint.h>

#define N_CUST 500000
#define N_FUND 50000
#define N_EDGE 4000000
#define D_CUST 101
#define HID 64

#define NB   512                              // reorder blocks (measured-good R0)
#define EPB  ((N_EDGE + NB - 1) / NB)         // 7813 edges per block
#define CB   512                              // customers per bucket
#define NBKT ((N_CUST + CB - 1) / CB)         // 977 buckets
#define CAP  5120                             // per-bucket capacity (mean 4096, +16 sigma)
#define GPAD 32                               // gcur padding: 1 counter per 128B line

typedef float float4u __attribute__((ext_vector_type(4), aligned(4)));
using frag_ab = __attribute__((ext_vector_type(8))) short;   // 8 bf16
using frag_cd = __attribute__((ext_vector_type(4))) float;   // 4 f32

struct __align__(16) Accum { float g0, g1, cnt, pad; };

__device__ __forceinline__ short f2bf(float f) {
    unsigned u = __float_as_uint(f);
    u += 0x7fffu + ((u >> 16) & 1u);          // round-to-nearest-even
    return (short)(u >> 16);
}

// A-fragment load for one 16-row tile; 7 VMEM loads issued up front.
__device__ __forceinline__ void load_af(const float* __restrict__ xr, int q,
                                        frag_ab af[4]) {
    #pragma unroll
    for (int kc = 0; kc < 3; ++kc) {
        float4u lo = *(const float4u*)(xr + kc * 32 + q * 8);
        float4u hi = *(const float4u*)(xr + kc * 32 + q * 8 + 4);
        frag_ab f;
        f[0]=f2bf(lo[0]); f[1]=f2bf(lo[1]); f[2]=f2bf(lo[2]); f[3]=f2bf(lo[3]);
        f[4]=f2bf(hi[0]); f[5]=f2bf(hi[1]); f[6]=f2bf(hi[2]); f[7]=f2bf(hi[3]);
        af[kc] = f;
    }
    frag_ab f = {0,0,0,0,0,0,0,0};
    if (q == 0) {                             // tail k = 96..100
        float4u lo = *(const float4u*)(xr + 96);
        f[0]=f2bf(lo[0]); f[1]=f2bf(lo[1]); f[2]=f2bf(lo[2]); f[3]=f2bf(lo[3]);
        f[4]=f2bf(xr[100]);
    }
    af[3] = f;
}

// ---------------------------------------------------------------------------
// k_gf: gf[f] = relu(x_f[f]*W_fund + b_fund) @ (W_l @ W_out)
// Block 0 additionally precomputes Bt = W_r@W_out, c2 = b_l@W_out + b_out,
// wcb = W_cust in bf16 MFMA B-fragment layout, and zeroes gcur (padded).
// Optional Az != nullptr: zero the 8MB Accum array (fallback path only).
// ---------------------------------------------------------------------------
__global__ __launch_bounds__(256) void k_gf(
    const float* __restrict__ x_fund,
    const float* __restrict__ W_fund,
    const float* __restrict__ b_fund,
    const float* __restrict__ W_l,
    const float* __restrict__ W_r,
    const float* __restrict__ W_out,
    const float* __restrict__ Wc,
    const float* __restrict__ b_l,
    const float* __restrict__ b_out,
    float2* __restrict__ gf,
    frag_ab* __restrict__ wcb,
    float* __restrict__ Bt,
    float* __restrict__ c2,
    unsigned* __restrict__ gcur,
    float4* __restrict__ Az)
{
    __shared__ float sAf[128];
    __shared__ float sWf[64];
    __shared__ float sBf[64];
    int t = threadIdx.x;

    if (Az != nullptr) {
        float4 z4 = make_float4(0.f, 0.f, 0.f, 0.f);
        for (int i = blockIdx.x * 256 + t; i < N_CUST; i += gridDim.x * 256)
            Az[i] = z4;
    }

    if (t < 128) {
        int h = t >> 1, j = t & 1;
        float s = 0.f;
        for (int k = 0; k < 64; ++k)
            s = fmaf(W_l[h * 64 + k], W_out[k * 2 + j], s);
        sAf[t] = s;
    } else if (t < 192) {
        sWf[t - 128] = W_fund[t - 128];
    } else {
        sBf[t - 192] = b_fund[t - 192];
    }
    __syncthreads();

    int f = blockIdx.x * 256 + t;
    if (f < N_FUND) {
        float xf = x_fund[f];
        float g0 = 0.f, g1 = 0.f;
        #pragma unroll
        for (int h = 0; h < 64; ++h) {
            float hf = fmaxf(fmaf(xf, sWf[h], sBf[h]), 0.f);
            g0 = fmaf(hf, sAf[2 * h + 0], g0);
            g1 = fmaf(hf, sAf[2 * h + 1], g1);
        }
        gf[f] = make_float2(g0, g1);
    }

    if (blockIdx.x == 0) {
        for (int k = t; k < NBKT * GPAD; k += 256) gcur[k] = 0u;
        if (t < 128) {
            int h = t >> 1, j = t & 1;
            float s = 0.f;
            for (int k = 0; k < 64; ++k)
                s = fmaf(W_r[h * 64 + k], W_out[k * 2 + j], s);
            Bt[t] = s;
        } else if (t < 130) {
            int j = t - 128;
            float s = b_out[j];
            for (int k = 0; k < 64; ++k)
                s = fmaf(b_l[k], W_out[k * 2 + j], s);
            c2[j] = s;
        }
        // wcb[(nt*4+kc)*64 + lane] = B-fragment for that (nt,kc,lane)
        for (int sidx = t; sidx < 1024; sidx += 256) {
            int fidx = sidx >> 6, l = sidx & 63;
            int c = l & 15, q = l >> 4;
            int nt = fidx >> 2, kc = fidx & 3;
            frag_ab fr;
            #pragma unroll
            for (int j = 0; j < 8; ++j) {
                int kk = kc * 32 + q * 8 + j;
                int h  = nt * 16 + c;
                fr[j] = (kk < D_CUST) ? f2bf(Wc[kk * HID + h]) : (short)0;
            }
            wcb[sidx] = fr;
        }
    }
}

// ---------------------------------------------------------------------------
// k_reorder: R0 flush structure (LDS bucket-sort, chunk reservation,
// coalesced flush via ldsBkt), but 512 threads/block: same 62.5KB LDS ->
// still 2 blocks/CU, but 16 waves/CU instead of 8 for the latency-bound
// load/scatter/flush phases. Strides 256 -> 512 only; structure unchanged.
// rec = src | (dst_local << 16); bucket = dst >> 9; dl = dst & 511.
// ---------------------------------------------------------------------------
__global__ __launch_bounds__(512) void k_reorder(
    const int* __restrict__ src, const int* __restrict__ dst,
    unsigned* __restrict__ gcur, unsigned* __restrict__ recs)
{
    __shared__ unsigned hist[NBKT];
    __shared__ unsigned localOff[NBKT];
    __shared__ unsigned cur[NBKT];
    __shared__ unsigned baseG[NBKT];
    __shared__ unsigned ldsRec[EPB];
    __shared__ unsigned short ldsBkt[EPB];

    int t = threadIdx.x, b = blockIdx.x;
    int e0 = b * EPB, e1 = min(e0 + EPB, N_EDGE);
    int cntE = e1 - e0;

    for (int k = t; k < NBKT; k += 512) hist[k] = 0;
    __syncthreads();
    for (int e = e0 + t; e < e1; e += 512)
        atomicAdd(&hist[((unsigned)dst[e]) >> 9], 1u);
    __syncthreads();

    // one-wave exclusive scan of hist[0..NBKT)
    if (t < 64) {
        unsigned v[16], pre[16], run = 0;
        #pragma unroll
        for (int j = 0; j < 16; ++j) {
            int idx = t * 16 + j;
            v[j] = (idx < NBKT) ? hist[idx] : 0u;
            pre[j] = run; run += v[j];
        }
        unsigned sc = run;
        #pragma unroll
        for (int d = 1; d < 64; d <<= 1) {
            unsigned n = __shfl_up(sc, d, 64);
            if (t >= d) sc += n;
        }
        unsigned lane_excl = sc - run;
        #pragma unroll
        for (int j = 0; j < 16; ++j) {
            int idx = t * 16 + j;
            if (idx < NBKT) {
                localOff[idx] = lane_excl + pre[j];
                cur[idx]      = lane_excl + pre[j];
            }
        }
    }
    __syncthreads();

    // reserve global chunks (one atomic per non-empty bucket, padded counter)
    for (int k = t; k < NBKT; k += 512) {
        unsigned h = hist[k];
        baseG[k] = h ? ((unsigned)k * CAP + atomicAdd(&gcur[k * GPAD], h)) : 0u;
    }

    // LDS scatter
    for (int e = e0 + t; e < e1; e += 512) {
        unsigned d = (unsigned)dst[e];
        unsigned s = (unsigned)src[e];
        unsigned k = d >> 9;
        unsigned p = atomicAdd(&cur[k], 1u);
        ldsRec[p] = s | ((d & 511u) << 16);
        ldsBkt[p] = (unsigned short)k;
    }
    __syncthreads();

    // coalesced flush (bucket-sorted order -> consecutive i = consecutive g)
    for (int i = t; i < cntE; i += 512) {
        unsigned k = ldsBkt[i];
        unsigned g = baseG[k] + (i - localOff[k]);
        if (g < (k + 1u) * CAP) recs[g] = ldsRec[i];
    }
}

// ---------------------------------------------------------------------------
// k_bucket v6: wave-split + work-stealing + in-register epilogue, with
// 2-tile unrolled steal (14 A-loads in flight vs 7; half the steal syncs)
// and 8-record agg unroll (8 gf gathers in flight). Same 10.5KB LDS.
// No occupancy pin (R6 lesson: pin -> 40 VGPR -> bfrag spill -> 1.6x slower).
// ---------------------------------------------------------------------------
__global__ __launch_bounds__(256) void k_bucket(
    const unsigned* __restrict__ recs, const unsigned* __restrict__ gcur,
    const float2* __restrict__ gf,
    const float* __restrict__ x, const float* __restrict__ bc,
    const frag_ab* __restrict__ wcb, const float* __restrict__ Bt,
    const float* __restrict__ c2,
    float2* __restrict__ out)
{
    __shared__ float s0[CB], s1[CB], scn[CB];   // 6 KB
    __shared__ float pbuf[2 * CB];              // 4 KB
    __shared__ int tileCtr;

    int t = threadIdx.x, k = blockIdx.x;
    int w = t >> 6, lane = t & 63;
    int c = lane & 15, q = lane >> 4;

    if (t == 0) tileCtr = 0;
    for (int cc = t; cc < CB; cc += 256) { s0[cc] = 0.f; s1[cc] = 0.f; scn[cc] = 0.f; }
    __syncthreads();

    // per-wave constants (all waves GEMM eventually)
    frag_ab bfrag[16];
    #pragma unroll
    for (int f = 0; f < 16; ++f) bfrag[f] = wcb[f * 64 + lane];
    float btv[8];                                // Bt[(nt*16+c)][j]
    #pragma unroll
    for (int nt = 0; nt < 4; ++nt) {
        btv[2 * nt]     = Bt[(nt * 16 + c) * 2];
        btv[2 * nt + 1] = Bt[(nt * 16 + c) * 2 + 1];
    }
    float bcv[4];
    #pragma unroll
    for (int nt = 0; nt < 4; ++nt) bcv[nt] = bc[nt * 16 + c];
    float c20 = c2[0], c21 = c2[1];

    int cust0 = k * CB;
    int ncust = min(CB, N_CUST - cust0);
    int n_tiles = ncust >> 4;                   // 32, or 18 for last bucket

    if (w == 3) {
        // ------------ aggregation (then joins the steal loop) ------------
        unsigned n = min(gcur[(unsigned)k * GPAD], (unsigned)CAP);
        const unsigned* rp = recs + (size_t)k * CAP;
        unsigned i = (unsigned)lane * 8u;
        for (; i + 8u <= n; i += 512u) {
            uint4 ra = *(const uint4*)(rp + i);
            uint4 rb = *(const uint4*)(rp + i + 4);
            float2 g0 = gf[ra.x & 0xFFFFu];
            float2 g1 = gf[ra.y & 0xFFFFu];
            float2 g2 = gf[ra.z & 0xFFFFu];
            float2 g3 = gf[ra.w & 0xFFFFu];
            float2 g4 = gf[rb.x & 0xFFFFu];
            float2 g5 = gf[rb.y & 0xFFFFu];
            float2 g6 = gf[rb.z & 0xFFFFu];
            float2 g7 = gf[rb.w & 0xFFFFu];
            unsigned d0 = ra.x >> 16, d1 = ra.y >> 16, d2 = ra.z >> 16, d3 = ra.w >> 16;
            unsigned d4 = rb.x >> 16, d5 = rb.y >> 16, d6 = rb.z >> 16, d7 = rb.w >> 16;
            atomicAdd(&s0[d0], g0.x); atomicAdd(&s1[d0], g0.y); atomicAdd(&scn[d0], 1.f);
            atomicAdd(&s0[d1], g1.x); atomicAdd(&s1[d1], g1.y); atomicAdd(&scn[d1], 1.f);
            atomicAdd(&s0[d2], g2.x); atomicAdd(&s1[d2], g2.y); atomicAdd(&scn[d2], 1.f);
            atomicAdd(&s0[d3], g3.x); atomicAdd(&s1[d3], g3.y); atomicAdd(&scn[d3], 1.f);
            atomicAdd(&s0[d4], g4.x); atomicAdd(&s1[d4], g4.y); atomicAdd(&scn[d4], 1.f);
            atomicAdd(&s0[d5], g5.x); atomicAdd(&s1[d5], g5.y); atomicAdd(&scn[d5], 1.f);
            atomicAdd(&s0[d6], g6.x); atomicAdd(&s1[d6], g6.y); atomicAdd(&scn[d6], 1.f);
            atomicAdd(&s0[d7], g7.x); atomicAdd(&s1[d7], g7.y); atomicAdd(&scn[d7], 1.f);
        }
        for (unsigned j = (n & ~7u) + (unsigned)lane; j < n; j += 64u) {
            unsigned r = rp[j];
            float2 g = gf[r & 0xFFFFu];
            unsigned dl = r >> 16;
            atomicAdd(&s0[dl], g.x); atomicAdd(&s1[dl], g.y); atomicAdd(&scn[dl], 1.f);
        }
    }

    // ------------ work-stealing GEMM, 2 tiles per steal ------------
    for (;;) {
        int tl0;
        if (lane == 0) tl0 = atomicAdd(&tileCtr, 2);
        tl0 = __shfl(tl0, 0, 64);
        if (tl0 >= n_tiles) break;
        bool has2 = (tl0 + 1 < n_tiles);
        int tl1 = has2 ? tl0 + 1 : tl0;

        const float* xr0 = x + (size_t)(cust0 + tl0 * 16 + c) * D_CUST;
        const float* xr1 = x + (size_t)(cust0 + tl1 * 16 + c) * D_CUST;
        frag_ab af0[4], af1[4];
        load_af(xr0, q, af0);                  // 14 loads in flight before
        load_af(xr1, q, af1);                  // any MFMA consumes them

        // ---- tile 0 ----
        frag_cd acc[4];
        #pragma unroll
        for (int nt = 0; nt < 4; ++nt)
            acc[nt] = (frag_cd){bcv[nt], bcv[nt], bcv[nt], bcv[nt]};
        #pragma unroll
        for (int kc = 0; kc < 4; ++kc)
            #pragma unroll
            for (int nt = 0; nt < 4; ++nt)
                acc[nt] = __builtin_amdgcn_mfma_f32_16x16x32_bf16(
                    af0[kc], bfrag[nt * 4 + kc], acc[nt], 0, 0, 0);
        #pragma unroll
        for (int i = 0; i < 4; ++i) {
            float p0 = 0.f, p1 = 0.f;
            #pragma unroll
            for (int nt = 0; nt < 4; ++nt) {
                float zv = fmaxf(acc[nt][i], 0.f);
                p0 = fmaf(zv, btv[2 * nt],     p0);
                p1 = fmaf(zv, btv[2 * nt + 1], p1);
            }
            #pragma unroll
            for (int m = 1; m < 16; m <<= 1) {
                p0 += __shfl_xor(p0, m, 16);
                p1 += __shfl_xor(p1, m, 16);
            }
            if (c == 0) {
                int lrow = tl0 * 16 + q * 4 + i;
                pbuf[2 * lrow]     = p0 + c20;
                pbuf[2 * lrow + 1] = p1 + c21;
            }
        }

        // ---- tile 1 (acc reused) ----
        #pragma unroll
        for (int nt = 0; nt < 4; ++nt)
            acc[nt] = (frag_cd){bcv[nt], bcv[nt], bcv[nt], bcv[nt]};
        #pragma unroll
        for (int kc = 0; kc < 4; ++kc)
            #pragma unroll
            for (int nt = 0; nt < 4; ++nt)
                acc[nt] = __builtin_amdgcn_mfma_f32_16x16x32_bf16(
                    af1[kc], bfrag[nt * 4 + kc], acc[nt], 0, 0, 0);
        #pragma unroll
        for (int i = 0; i < 4; ++i) {
            float p0 = 0.f, p1 = 0.f;
            #pragma unroll
            for (int nt = 0; nt < 4; ++nt) {
                float zv = fmaxf(acc[nt][i], 0.f);
                p0 = fmaf(zv, btv[2 * nt],     p0);
                p1 = fmaf(zv, btv[2 * nt + 1], p1);
            }
            #pragma unroll
            for (int m = 1; m < 16; m <<= 1) {
                p0 += __shfl_xor(p0, m, 16);
                p1 += __shfl_xor(p1, m, 16);
            }
            if (c == 0 && has2) {
                int lrow = tl1 * 16 + q * 4 + i;
                pbuf[2 * lrow]     = p0 + c20;
                pbuf[2 * lrow + 1] = p1 + c21;
            }
        }
    }
    __syncthreads();

    // epilogue: combine GEMM result with neighbor mean, coalesced write
    for (int cc = t; cc < ncust; cc += 256) {
        float inv = 1.0f / fmaxf(scn[cc], 1.0f);
        out[cust0 + cc] = make_float2(fmaf(s0[cc], inv, pbuf[2 * cc]),
                                      fmaf(s1[cc], inv, pbuf[2 * cc + 1]));
    }
}

// ---------------------------------------------------------------------------
// Fallback-path kernels (direct global atomics) if ws too small for recs.
// ---------------------------------------------------------------------------
__global__ __launch_bounds__(256) void k_scatter_direct(
    const int* __restrict__ src, const int* __restrict__ dst,
    const float2* __restrict__ gf, Accum* __restrict__ A)
{
    int stride = gridDim.x * 256;
    for (int e = blockIdx.x * 256 + threadIdx.x; e < N_EDGE; e += stride) {
        int s = src[e], d = dst[e];
        float2 g = gf[s];
        unsafeAtomicAdd(&A[d].g0, g.x);
        unsafeAtomicAdd(&A[d].g1, g.y);
        unsafeAtomicAdd(&A[d].cnt, 1.0f);
    }
}

__global__ __launch_bounds__(256) void k_mean(
    const Accum* __restrict__ A, float2* __restrict__ mean2)
{
    int i = blockIdx.x * 256 + threadIdx.x;
    if (i < N_CUST) {
        Accum a = A[i];
        float inv = 1.0f / fmaxf(a.cnt, 1.0f);
        mean2[i] = make_float2(a.g0 * inv, a.g1 * inv);
    }
}

__global__ __launch_bounds__(256) void k_gemm(
    const float* __restrict__ x, const float* __restrict__ bc,
    const frag_ab* __restrict__ wcb, const float* __restrict__ Bt,
    const float* __restrict__ c2, const float2* __restrict__ mean2,
    float2* __restrict__ out)
{
    __shared__ float sBt[128];
    __shared__ float zb[4][16 * 68];

    int t = threadIdx.x;
    int w = t >> 6, lane = t & 63;
    int c = lane & 15, q = lane >> 4;
    float* z = zb[w];

    if (t < 128) sBt[t] = Bt[t];
    frag_ab bfrag[16];
    #pragma unroll
    for (int f = 0; f < 16; ++f) bfrag[f] = wcb[f * 64 + lane];
    float bcv[4];
    #pragma unroll
    for (int nt = 0; nt < 4; ++nt) bcv[nt] = bc[nt * 16 + c];
    float c20 = c2[0], c21 = c2[1];
    __syncthreads();

    const int NT = N_CUST / 16;
    for (int tl = blockIdx.x * 4 + w; tl < NT; tl += gridDim.x * 4) {
        int row0 = tl * 16;
        const float* xr = x + (size_t)(row0 + c) * D_CUST;
        frag_ab af[4];
        load_af(xr, q, af);
        frag_cd acc[4];
        #pragma unroll
        for (int nt = 0; nt < 4; ++nt)
            acc[nt] = (frag_cd){bcv[nt], bcv[nt], bcv[nt], bcv[nt]};
        #pragma unroll
        for (int kc = 0; kc < 4; ++kc)
            #pragma unroll
            for (int nt = 0; nt < 4; ++nt)
                acc[nt] = __builtin_amdgcn_mfma_f32_16x16x32_bf16(
                    af[kc], bfrag[nt * 4 + kc], acc[nt], 0, 0, 0);
        #pragma unroll
        for (int nt = 0; nt < 4; ++nt)
            #pragma unroll
            for (int i = 0; i < 4; ++i)
                z[(q * 4 + i) * 68 + nt * 16 + c] = fmaxf(acc[nt][i], 0.f);
        float p0 = 0.f, p1 = 0.f;
        #pragma unroll
        for (int j4 = 0; j4 < 4; ++j4) {
            float4u zv = *(const float4u*)(z + c * 68 + q * 16 + j4 * 4);
            float4u b0 = *(const float4u*)(sBt + q * 32 + j4 * 8);
            float4u b1 = *(const float4u*)(sBt + q * 32 + j4 * 8 + 4);
            p0 = fmaf(zv[0], b0[0], p0); p1 = fmaf(zv[0], b0[1], p1);
            p0 = fmaf(zv[1], b0[2], p0); p1 = fmaf(zv[1], b0[3], p1);
            p0 = fmaf(zv[2], b1[0], p0); p1 = fmaf(zv[2], b1[1], p1);
            p0 = fmaf(zv[3], b1[2], p0); p1 = fmaf(zv[3], b1[3], p1);
        }
        p0 += __shfl_xor(p0, 16, 64); p0 += __shfl_xor(p0, 32, 64);
        p1 += __shfl_xor(p1, 16, 64); p1 += __shfl_xor(p1, 32, 64);
        if (q == 0) {
            float2 m = mean2[row0 + c];
            out[row0 + c] = make_float2(p0 + c20 + m.x, p1 + c21 + m.y);
        }
    }
}

// ---------------------------------------------------------------------------
extern "C" void kernel_launch(void* const* d_in, const int* in_sizes, int n_in,
                              void* d_out, int out_size, void* d_ws, size_t ws_size,
                              hipStream_t stream) {
    const float* x_customer = (const float*)d_in[0];
    const float* x_fund     = (const float*)d_in[1];
    const int*   src_fund   = (const int*)d_in[2];
    const int*   dst_cust   = (const int*)d_in[3];
    const float* W_cust     = (const float*)d_in[4];
    const float* b_cust     = (const float*)d_in[5];
    const float* W_fund     = (const float*)d_in[6];
    const float* b_fund     = (const float*)d_in[7];
    const float* W_l        = (const float*)d_in[8];
    const float* b_l        = (const float*)d_in[9];
    const float* W_r        = (const float*)d_in[10];
    const float* W_out      = (const float*)d_in[11];
    const float* b_out      = (const float*)d_in[12];

    char* ws = (char*)d_ws;
    // fast path layout:
    //   recs @ 0          : 977*5120*4 = 20,008,960
    //   gf   @ 20,008,960 :   400,000
    //   wcb  @ 20,408,960 :    16,384
    //   Bt   @ 20,425,344 :       512
    //   c2   @ 20,425,856 :        64
    //   gcur @ 20,425,920 :   125,056  (977*32*4, padded) -> total 20,550,976
    const size_t NEED_FAST = 20550976ull;

    if (ws_size >= NEED_FAST) {
        unsigned* recs = (unsigned*)(ws);
        float2*   gf   = (float2*)  (ws + 20008960);
        frag_ab*  wcb  = (frag_ab*) (ws + 20408960);
        float*    Bt   = (float*)   (ws + 20425344);
        float*    c2   = (float*)   (ws + 20425856);
        unsigned* gcur = (unsigned*)(ws + 20425920);

        k_gf<<<256, 256, 0, stream>>>(
            x_fund, W_fund, b_fund, W_l, W_r, W_out, W_cust, b_l, b_out,
            gf, wcb, Bt, c2, gcur, nullptr);
        k_reorder<<<NB, 512, 0, stream>>>(src_fund, dst_cust, gcur, recs);
        k_bucket<<<NBKT, 256, 0, stream>>>(
            recs, gcur, gf, x_customer, b_cust, wcb, Bt, c2, (float2*)d_out);
    } else {
        // fallback: A 8,000,000 | mean2 4,000,000 | gf 400,000 | wcb 16,384
        //           | Bt 512 | c2 64 | gcur 125,056 -> 12,542,016
        Accum*    A    = (Accum*)   (ws);
        float2*   mn2  = (float2*)  (ws + 8000000);
        float2*   gf   = (float2*)  (ws + 12000000);
        frag_ab*  wcb  = (frag_ab*) (ws + 12400000);
        float*    Bt   = (float*)   (ws + 12416384);
        float*    c2   = (float*)   (ws + 12416896);
        unsigned* gcur = (unsigned*)(ws + 12416960);

        k_gf<<<256, 256, 0, stream>>>(
            x_fund, W_fund, b_fund, W_l, W_r, W_out, W_cust, b_l, b_out,
            gf, wcb, Bt, c2, gcur, (float4*)A);
        k_scatter_direct<<<2048, 256, 0, stream>>>(src_fund, dst_cust, gf, A);
        k_mean<<<(N_CUST + 255) / 256, 256, 0, stream>>>(A, mn2);
        k_gemm<<<2048, 256, 0, stream>>>(
            x_customer, b_cust, wcb, Bt, c2, mn2, (float2*)d_out);
    }
}

// Round 9
// 427.593 us; speedup vs baseline: 1.1353x; 1.0020x over previous
//
#include <hip/hip_runtime.h>
#include <stdint.h>

#define N_CUST 500000
#define N_FUND 50000
#define N_EDGE 4000000
#define D_CUST 101
#define HID 64

#define NB   512                              // reorder blocks (measured-good R0)
#define EPB  ((N_EDGE + NB - 1) / NB)         // 7813 edges per block
#define CB   512                              // customers per bucket
#define NBKT ((N_CUST + CB - 1) / CB)         // 977 buckets
#define CAP  5120                             // per-bucket capacity (mean 4096, +16 sigma)
#define GPAD 32                               // gcur padding: 1 counter per 128B line
#define SPLIT 4                               // sub-blocks per bucket
#define CSUB (CB / SPLIT)                     // 128 customers per sub-block

typedef float float4u __attribute__((ext_vector_type(4), aligned(4)));
using frag_ab = __attribute__((ext_vector_type(8))) short;   // 8 bf16
using frag_cd = __attribute__((ext_vector_type(4))) float;   // 4 f32

struct __align__(16) Accum { float g0, g1, cnt, pad; };

__device__ __forceinline__ short f2bf(float f) {
    unsigned u = __float_as_uint(f);
    u += 0x7fffu + ((u >> 16) & 1u);          // round-to-nearest-even
    return (short)(u >> 16);
}

// A-fragment load for one 16-row tile; 7 VMEM loads issued up front.
__device__ __forceinline__ void load_af(const float* __restrict__ xr, int q,
                                        frag_ab af[4]) {
    #pragma unroll
    for (int kc = 0; kc < 3; ++kc) {
        float4u lo = *(const float4u*)(xr + kc * 32 + q * 8);
        float4u hi = *(const float4u*)(xr + kc * 32 + q * 8 + 4);
        frag_ab f;
        f[0]=f2bf(lo[0]); f[1]=f2bf(lo[1]); f[2]=f2bf(lo[2]); f[3]=f2bf(lo[3]);
        f[4]=f2bf(hi[0]); f[5]=f2bf(hi[1]); f[6]=f2bf(hi[2]); f[7]=f2bf(hi[3]);
        af[kc] = f;
    }
    frag_ab f = {0,0,0,0,0,0,0,0};
    if (q == 0) {                             // tail k = 96..100
        float4u lo = *(const float4u*)(xr + 96);
        f[0]=f2bf(lo[0]); f[1]=f2bf(lo[1]); f[2]=f2bf(lo[2]); f[3]=f2bf(lo[3]);
        f[4]=f2bf(xr[100]);
    }
    af[3] = f;
}

// MFMA tile + in-register z@Bt epilogue -> pbuf (local 2*CSUB floats)
__device__ __forceinline__ void gemm_tile(
    const frag_ab af[4], const frag_ab bfrag[16], const float bcv[4],
    const float btv[8], float c20, float c21, int tl, int q, int c,
    float* __restrict__ pbuf) {
    frag_cd acc[4];
    #pragma unroll
    for (int nt = 0; nt < 4; ++nt)
        acc[nt] = (frag_cd){bcv[nt], bcv[nt], bcv[nt], bcv[nt]};
    #pragma unroll
    for (int kc = 0; kc < 4; ++kc)
        #pragma unroll
        for (int nt = 0; nt < 4; ++nt)
            acc[nt] = __builtin_amdgcn_mfma_f32_16x16x32_bf16(
                af[kc], bfrag[nt * 4 + kc], acc[nt], 0, 0, 0);
    #pragma unroll
    for (int i = 0; i < 4; ++i) {
        float p0 = 0.f, p1 = 0.f;
        #pragma unroll
        for (int nt = 0; nt < 4; ++nt) {
            float zv = fmaxf(acc[nt][i], 0.f);
            p0 = fmaf(zv, btv[2 * nt],     p0);
            p1 = fmaf(zv, btv[2 * nt + 1], p1);
        }
        #pragma unroll
        for (int m = 1; m < 16; m <<= 1) {
            p0 += __shfl_xor(p0, m, 16);
            p1 += __shfl_xor(p1, m, 16);
        }
        if (c == 0) {
            int lrow = tl * 16 + q * 4 + i;
            pbuf[2 * lrow]     = p0 + c20;
            pbuf[2 * lrow + 1] = p1 + c21;
        }
    }
}

// ---------------------------------------------------------------------------
// k_gf: gf[f] = relu(x_f[f]*W_fund + b_fund) @ (W_l @ W_out)
// Block 0 additionally precomputes Bt = W_r@W_out, c2 = b_l@W_out + b_out,
// wcb = W_cust in bf16 MFMA B-fragment layout, and zeroes gcur (padded).
// Optional Az != nullptr: zero the 8MB Accum array (fallback path only).
// ---------------------------------------------------------------------------
__global__ __launch_bounds__(256) void k_gf(
    const float* __restrict__ x_fund,
    const float* __restrict__ W_fund,
    const float* __restrict__ b_fund,
    const float* __restrict__ W_l,
    const float* __restrict__ W_r,
    const float* __restrict__ W_out,
    const float* __restrict__ Wc,
    const float* __restrict__ b_l,
    const float* __restrict__ b_out,
    float2* __restrict__ gf,
    frag_ab* __restrict__ wcb,
    float* __restrict__ Bt,
    float* __restrict__ c2,
    unsigned* __restrict__ gcur,
    float4* __restrict__ Az)
{
    __shared__ float sAf[128];
    __shared__ float sWf[64];
    __shared__ float sBf[64];
    int t = threadIdx.x;

    if (Az != nullptr) {
        float4 z4 = make_float4(0.f, 0.f, 0.f, 0.f);
        for (int i = blockIdx.x * 256 + t; i < N_CUST; i += gridDim.x * 256)
            Az[i] = z4;
    }

    if (t < 128) {
        int h = t >> 1, j = t & 1;
        float s = 0.f;
        for (int k = 0; k < 64; ++k)
            s = fmaf(W_l[h * 64 + k], W_out[k * 2 + j], s);
        sAf[t] = s;
    } else if (t < 192) {
        sWf[t - 128] = W_fund[t - 128];
    } else {
        sBf[t - 192] = b_fund[t - 192];
    }
    __syncthreads();

    int f = blockIdx.x * 256 + t;
    if (f < N_FUND) {
        float xf = x_fund[f];
        float g0 = 0.f, g1 = 0.f;
        #pragma unroll
        for (int h = 0; h < 64; ++h) {
            float hf = fmaxf(fmaf(xf, sWf[h], sBf[h]), 0.f);
            g0 = fmaf(hf, sAf[2 * h + 0], g0);
            g1 = fmaf(hf, sAf[2 * h + 1], g1);
        }
        gf[f] = make_float2(g0, g1);
    }

    if (blockIdx.x == 0) {
        for (int k = t; k < NBKT * GPAD; k += 256) gcur[k] = 0u;
        if (t < 128) {
            int h = t >> 1, j = t & 1;
            float s = 0.f;
            for (int k = 0; k < 64; ++k)
                s = fmaf(W_r[h * 64 + k], W_out[k * 2 + j], s);
            Bt[t] = s;
        } else if (t < 130) {
            int j = t - 128;
            float s = b_out[j];
            for (int k = 0; k < 64; ++k)
                s = fmaf(b_l[k], W_out[k * 2 + j], s);
            c2[j] = s;
        }
        // wcb[(nt*4+kc)*64 + lane] = B-fragment for that (nt,kc,lane)
        for (int sidx = t; sidx < 1024; sidx += 256) {
            int fidx = sidx >> 6, l = sidx & 63;
            int c = l & 15, q = l >> 4;
            int nt = fidx >> 2, kc = fidx & 3;
            frag_ab fr;
            #pragma unroll
            for (int j = 0; j < 8; ++j) {
                int kk = kc * 32 + q * 8 + j;
                int h  = nt * 16 + c;
                fr[j] = (kk < D_CUST) ? f2bf(Wc[kk * HID + h]) : (short)0;
            }
            wcb[sidx] = fr;
        }
    }
}

// ---------------------------------------------------------------------------
// k_reorder: R0 flush structure (LDS bucket-sort, chunk reservation,
// coalesced flush via ldsBkt), 512 threads (R8). Unchanged.
// rec = src | (dst_local << 16); bucket = dst >> 9; dl = dst & 511.
// ---------------------------------------------------------------------------
__global__ __launch_bounds__(512) void k_reorder(
    const int* __restrict__ src, const int* __restrict__ dst,
    unsigned* __restrict__ gcur, unsigned* __restrict__ recs)
{
    __shared__ unsigned hist[NBKT];
    __shared__ unsigned localOff[NBKT];
    __shared__ unsigned cur[NBKT];
    __shared__ unsigned baseG[NBKT];
    __shared__ unsigned ldsRec[EPB];
    __shared__ unsigned short ldsBkt[EPB];

    int t = threadIdx.x, b = blockIdx.x;
    int e0 = b * EPB, e1 = min(e0 + EPB, N_EDGE);
    int cntE = e1 - e0;

    for (int k = t; k < NBKT; k += 512) hist[k] = 0;
    __syncthreads();
    for (int e = e0 + t; e < e1; e += 512)
        atomicAdd(&hist[((unsigned)dst[e]) >> 9], 1u);
    __syncthreads();

    // one-wave exclusive scan of hist[0..NBKT)
    if (t < 64) {
        unsigned v[16], pre[16], run = 0;
        #pragma unroll
        for (int j = 0; j < 16; ++j) {
            int idx = t * 16 + j;
            v[j] = (idx < NBKT) ? hist[idx] : 0u;
            pre[j] = run; run += v[j];
        }
        unsigned sc = run;
        #pragma unroll
        for (int d = 1; d < 64; d <<= 1) {
            unsigned n = __shfl_up(sc, d, 64);
            if (t >= d) sc += n;
        }
        unsigned lane_excl = sc - run;
        #pragma unroll
        for (int j = 0; j < 16; ++j) {
            int idx = t * 16 + j;
            if (idx < NBKT) {
                localOff[idx] = lane_excl + pre[j];
                cur[idx]      = lane_excl + pre[j];
            }
        }
    }
    __syncthreads();

    // reserve global chunks (one atomic per non-empty bucket, padded counter)
    for (int k = t; k < NBKT; k += 512) {
        unsigned h = hist[k];
        baseG[k] = h ? ((unsigned)k * CAP + atomicAdd(&gcur[k * GPAD], h)) : 0u;
    }

    // LDS scatter
    for (int e = e0 + t; e < e1; e += 512) {
        unsigned d = (unsigned)dst[e];
        unsigned s = (unsigned)src[e];
        unsigned k = d >> 9;
        unsigned p = atomicAdd(&cur[k], 1u);
        ldsRec[p] = s | ((d & 511u) << 16);
        ldsBkt[p] = (unsigned short)k;
    }
    __syncthreads();

    // coalesced flush (bucket-sorted order -> consecutive i = consecutive g)
    for (int i = t; i < cntE; i += 512) {
        unsigned k = ldsBkt[i];
        unsigned g = baseG[k] + (i - localOff[k]);
        if (g < (k + 1u) * CAP) recs[g] = ldsRec[i];
    }
}

// ---------------------------------------------------------------------------
// k_bucket v7: 4 sub-blocks per bucket (grid NBKT*4), each owning 128
// customer rows. Fixes the 977-block grid limit (3.8 blocks/CU, 20%
// occupancy) that R0-R8 all shared, and spreads the 12.3M LDS atomic adds
// over 4x the resident waves.
//  Phase A: all 256 threads scan the bucket's records (uint4, L2/L3-hot),
//           FILTER to this sub-block's 128-row range, gather gf + 3 LDS
//           atomics only for matches (gf gathers stay 1x total).
//  Phase B: 8 tiles; wave w does tiles w and w+4 with dual A-load ILP (R8);
//           in-register z@Bt epilogue (R7).
// LDS ~2.6 KB -> occupancy limited only by wave slots (8 blocks/CU = 100%).
// No occupancy pin (R6 lesson: pin -> spill -> 1.6x slower).
// ---------------------------------------------------------------------------
__global__ __launch_bounds__(256) void k_bucket(
    const unsigned* __restrict__ recs, const unsigned* __restrict__ gcur,
    const float2* __restrict__ gf,
    const float* __restrict__ x, const float* __restrict__ bc,
    const frag_ab* __restrict__ wcb, const float* __restrict__ Bt,
    const float* __restrict__ c2,
    float2* __restrict__ out)
{
    __shared__ float s0[CSUB], s1[CSUB], scn[CSUB];   // 1.5 KB
    __shared__ float pbuf[2 * CSUB];                  // 1 KB

    int t = threadIdx.x;
    int k = blockIdx.x >> 2, sub = blockIdx.x & 3;
    int w = t >> 6, lane = t & 63;
    int c = lane & 15, q = lane >> 4;

    int cust0 = k * CB + sub * CSUB;
    if (cust0 >= N_CUST) return;                // last bucket: sub 3 empty
    int ncust = min(CSUB, N_CUST - cust0);
    int n_tiles = ncust >> 4;                   // 8, or 2 for the last sub

    if (t < CSUB) { s0[t] = 0.f; s1[t] = 0.f; scn[t] = 0.f; }
    __syncthreads();

    // issue per-wave constant loads early (in flight during phase A)
    frag_ab bfrag[16];
    #pragma unroll
    for (int f = 0; f < 16; ++f) bfrag[f] = wcb[f * 64 + lane];
    float btv[8];
    #pragma unroll
    for (int nt = 0; nt < 4; ++nt) {
        btv[2 * nt]     = Bt[(nt * 16 + c) * 2];
        btv[2 * nt + 1] = Bt[(nt * 16 + c) * 2 + 1];
    }
    float bcv[4];
    #pragma unroll
    for (int nt = 0; nt < 4; ++nt) bcv[nt] = bc[nt * 16 + c];
    float c20 = c2[0], c21 = c2[1];

    // ---------- phase A: filtered aggregation ----------
    unsigned n = min(gcur[(unsigned)k * GPAD], (unsigned)CAP);
    const unsigned* rp = recs + (size_t)k * CAP;
    unsigned dlo = (unsigned)sub * CSUB;        // range [dlo, dlo+128)
    for (unsigned i = (unsigned)t * 4u; i + 4u <= n; i += 1024u) {
        uint4 rr = *(const uint4*)(rp + i);
        unsigned rv[4] = {rr.x, rr.y, rr.z, rr.w};
        #pragma unroll
        for (int j = 0; j < 4; ++j) {
            unsigned dl = rv[j] >> 16;
            if ((dl & ~(unsigned)(CSUB - 1)) == dlo) {
                float2 g = gf[rv[j] & 0xFFFFu];
                unsigned d = dl & (CSUB - 1);
                atomicAdd(&s0[d], g.x);
                atomicAdd(&s1[d], g.y);
                atomicAdd(&scn[d], 1.f);
            }
        }
    }
    for (unsigned i = (n & ~3u) + (unsigned)t; i < n; i += 256u) {
        unsigned r = rp[i];
        unsigned dl = r >> 16;
        if ((dl & ~(unsigned)(CSUB - 1)) == dlo) {
            float2 g = gf[r & 0xFFFFu];
            unsigned d = dl & (CSUB - 1);
            atomicAdd(&s0[d], g.x);
            atomicAdd(&s1[d], g.y);
            atomicAdd(&scn[d], 1.f);
        }
    }

    // ---------- phase B: GEMM, wave w -> tiles w and w+4 ----------
    int tl0 = w, tl1 = w + 4;
    bool h0 = tl0 < n_tiles, h1 = tl1 < n_tiles;
    frag_ab af0[4], af1[4];
    if (h0) load_af(x + (size_t)(cust0 + tl0 * 16 + c) * D_CUST, q, af0);
    if (h1) load_af(x + (size_t)(cust0 + tl1 * 16 + c) * D_CUST, q, af1);
    if (h0) gemm_tile(af0, bfrag, bcv, btv, c20, c21, tl0, q, c, pbuf);
    if (h1) gemm_tile(af1, bfrag, bcv, btv, c20, c21, tl1, q, c, pbuf);
    __syncthreads();

    // ---------- epilogue: out = pbuf + s/cnt ----------
    for (int cc = t; cc < ncust; cc += 256) {
        float inv = 1.0f / fmaxf(scn[cc], 1.0f);
        out[cust0 + cc] = make_float2(fmaf(s0[cc], inv, pbuf[2 * cc]),
                                      fmaf(s1[cc], inv, pbuf[2 * cc + 1]));
    }
}

// ---------------------------------------------------------------------------
// Fallback-path kernels (direct global atomics) if ws too small for recs.
// ---------------------------------------------------------------------------
__global__ __launch_bounds__(256) void k_scatter_direct(
    const int* __restrict__ src, const int* __restrict__ dst,
    const float2* __restrict__ gf, Accum* __restrict__ A)
{
    int stride = gridDim.x * 256;
    for (int e = blockIdx.x * 256 + threadIdx.x; e < N_EDGE; e += stride) {
        int s = src[e], d = dst[e];
        float2 g = gf[s];
        unsafeAtomicAdd(&A[d].g0, g.x);
        unsafeAtomicAdd(&A[d].g1, g.y);
        unsafeAtomicAdd(&A[d].cnt, 1.0f);
    }
}

__global__ __launch_bounds__(256) void k_mean(
    const Accum* __restrict__ A, float2* __restrict__ mean2)
{
    int i = blockIdx.x * 256 + threadIdx.x;
    if (i < N_CUST) {
        Accum a = A[i];
        float inv = 1.0f / fmaxf(a.cnt, 1.0f);
        mean2[i] = make_float2(a.g0 * inv, a.g1 * inv);
    }
}

__global__ __launch_bounds__(256) void k_gemm(
    const float* __restrict__ x, const float* __restrict__ bc,
    const frag_ab* __restrict__ wcb, const float* __restrict__ Bt,
    const float* __restrict__ c2, const float2* __restrict__ mean2,
    float2* __restrict__ out)
{
    __shared__ float sBt[128];
    __shared__ float zb[4][16 * 68];

    int t = threadIdx.x;
    int w = t >> 6, lane = t & 63;
    int c = lane & 15, q = lane >> 4;
    float* z = zb[w];

    if (t < 128) sBt[t] = Bt[t];
    frag_ab bfrag[16];
    #pragma unroll
    for (int f = 0; f < 16; ++f) bfrag[f] = wcb[f * 64 + lane];
    float bcv[4];
    #pragma unroll
    for (int nt = 0; nt < 4; ++nt) bcv[nt] = bc[nt * 16 + c];
    float c20 = c2[0], c21 = c2[1];
    __syncthreads();

    const int NT = N_CUST / 16;
    for (int tl = blockIdx.x * 4 + w; tl < NT; tl += gridDim.x * 4) {
        int row0 = tl * 16;
        const float* xr = x + (size_t)(row0 + c) * D_CUST;
        frag_ab af[4];
        load_af(xr, q, af);
        frag_cd acc[4];
        #pragma unroll
        for (int nt = 0; nt < 4; ++nt)
            acc[nt] = (frag_cd){bcv[nt], bcv[nt], bcv[nt], bcv[nt]};
        #pragma unroll
        for (int kc = 0; kc < 4; ++kc)
            #pragma unroll
            for (int nt = 0; nt < 4; ++nt)
                acc[nt] = __builtin_amdgcn_mfma_f32_16x16x32_bf16(
                    af[kc], bfrag[nt * 4 + kc], acc[nt], 0, 0, 0);
        #pragma unroll
        for (int nt = 0; nt < 4; ++nt)
            #pragma unroll
            for (int i = 0; i < 4; ++i)
                z[(q * 4 + i) * 68 + nt * 16 + c] = fmaxf(acc[nt][i], 0.f);
        float p0 = 0.f, p1 = 0.f;
        #pragma unroll
        for (int j4 = 0; j4 < 4; ++j4) {
            float4u zv = *(const float4u*)(z + c * 68 + q * 16 + j4 * 4);
            float4u b0 = *(const float4u*)(sBt + q * 32 + j4 * 8);
            float4u b1 = *(const float4u*)(sBt + q * 32 + j4 * 8 + 4);
            p0 = fmaf(zv[0], b0[0], p0); p1 = fmaf(zv[0], b0[1], p1);
            p0 = fmaf(zv[1], b0[2], p0); p1 = fmaf(zv[1], b0[3], p1);
            p0 = fmaf(zv[2], b1[0], p0); p1 = fmaf(zv[2], b1[1], p1);
            p0 = fmaf(zv[3], b1[2], p0); p1 = fmaf(zv[3], b1[3], p1);
        }
        p0 += __shfl_xor(p0, 16, 64); p0 += __shfl_xor(p0, 32, 64);
        p1 += __shfl_xor(p1, 16, 64); p1 += __shfl_xor(p1, 32, 64);
        if (q == 0) {
            float2 m = mean2[row0 + c];
            out[row0 + c] = make_float2(p0 + c20 + m.x, p1 + c21 + m.y);
        }
    }
}

// ---------------------------------------------------------------------------
extern "C" void kernel_launch(void* const* d_in, const int* in_sizes, int n_in,
                              void* d_out, int out_size, void* d_ws, size_t ws_size,
                              hipStream_t stream) {
    const float* x_customer = (const float*)d_in[0];
    const float* x_fund     = (const float*)d_in[1];
    const int*   src_fund   = (const int*)d_in[2];
    const int*   dst_cust   = (const int*)d_in[3];
    const float* W_cust     = (const float*)d_in[4];
    const float* b_cust     = (const float*)d_in[5];
    const float* W_fund     = (const float*)d_in[6];
    const float* b_fund     = (const float*)d_in[7];
    const float* W_l        = (const float*)d_in[8];
    const float* b_l        = (const float*)d_in[9];
    const float* W_r        = (const float*)d_in[10];
    const float* W_out      = (const float*)d_in[11];
    const float* b_out      = (const float*)d_in[12];

    char* ws = (char*)d_ws;
    // fast path layout:
    //   recs @ 0          : 977*5120*4 = 20,008,960
    //   gf   @ 20,008,960 :   400,000
    //   wcb  @ 20,408,960 :    16,384
    //   Bt   @ 20,425,344 :       512
    //   c2   @ 20,425,856 :        64
    //   gcur @ 20,425,920 :   125,056  (977*32*4, padded) -> total 20,550,976
    const size_t NEED_FAST = 20550976ull;

    if (ws_size >= NEED_FAST) {
        unsigned* recs = (unsigned*)(ws);
        float2*   gf   = (float2*)  (ws + 20008960);
        frag_ab*  wcb  = (frag_ab*) (ws + 20408960);
        float*    Bt   = (float*)   (ws + 20425344);
        float*    c2   = (float*)   (ws + 20425856);
        unsigned* gcur = (unsigned*)(ws + 20425920);

        k_gf<<<256, 256, 0, stream>>>(
            x_fund, W_fund, b_fund, W_l, W_r, W_out, W_cust, b_l, b_out,
            gf, wcb, Bt, c2, gcur, nullptr);
        k_reorder<<<NB, 512, 0, stream>>>(src_fund, dst_cust, gcur, recs);
        k_bucket<<<NBKT * SPLIT, 256, 0, stream>>>(
            recs, gcur, gf, x_customer, b_cust, wcb, Bt, c2, (float2*)d_out);
    } else {
        // fallback: A 8,000,000 | mean2 4,000,000 | gf 400,000 | wcb 16,384
        //           | Bt 512 | c2 64 | gcur 125,056 -> 12,542,016
        Accum*    A    = (Accum*)   (ws);
        float2*   mn2  = (float2*)  (ws + 8000000);
        float2*   gf   = (float2*)  (ws + 12000000);
        frag_ab*  wcb  = (frag_ab*) (ws + 12400000);
        float*    Bt   = (float*)   (ws + 12416384);
        float*    c2   = (float*)   (ws + 12416896);
        unsigned* gcur = (unsigned*)(ws + 12416960);

        k_gf<<<256, 256, 0, stream>>>(
            x_fund, W_fund, b_fund, W_l, W_r, W_out, W_cust, b_l, b_out,
            gf, wcb, Bt, c2, gcur, (float4*)A);
        k_scatter_direct<<<2048, 256, 0, stream>>>(src_fund, dst_cust, gf, A);
        k_mean<<<(N_CUST + 255) / 256, 256, 0, stream>>>(A, mn2);
        k_gemm<<<2048, 256, 0, stream>>>(
            x_customer, b_cust, wcb, Bt, c2, mn2, (float2*)d_out);
    }
}